// Round 20
// baseline (136.621 us; speedup 1.0000x reference)
//
#include <hip/hip_runtime.h>
#include <hip/hip_bf16.h>
#include <math.h>
#include <string.h>

#define BATCH   4
#define SEQ     2044
#define DMODEL  512
#define DINNER  1024
#define NHEADS  16
#define HEADDIM 64
#define DSTATE  64
#define CONVDIM 1152
#define DINPROJ 2192
#define ZW      2176          // bf16-stored width of zxbcdt (z + xBC); dt cols -> fp32 lab
#define NROWS   (BATCH*SEQ)   // 8176
#define Q       64
#define NCHUNK  32

typedef __attribute__((ext_vector_type(8))) short bf16x8;
typedef __attribute__((ext_vector_type(4))) short short4v;
typedef __attribute__((ext_vector_type(4))) float f32x4;

#define MFMA(a,b,c) __builtin_amdgcn_mfma_f32_16x16x32_bf16((a),(b),(c),0,0,0)

__device__ inline short f2bf(float f) {
    __hip_bfloat16 h = __float2bfloat16(f);
    short s; memcpy(&s, &h, 2); return s;
}
__device__ inline float bf2f(short s) {
    unsigned u = ((unsigned)(unsigned short)s) << 16;
    float f; memcpy(&f, &u, 4); return f;
}
__device__ inline float bf2f_lo(unsigned u) {
    unsigned v = u << 16; float f; memcpy(&f, &v, 4); return f;
}
__device__ inline float bf2f_hi(unsigned u) {
    unsigned v = u & 0xffff0000u; float f; memcpy(&f, &v, 4); return f;
}

// async global->LDS, 16B per lane; LDS dest = wave-uniform base + lane*16
__device__ __forceinline__ void gload16(const short* g, short* l) {
    __builtin_amdgcn_global_load_lds(
        (const __attribute__((address_space(1))) void*)g,
        (__attribute__((address_space(3))) void*)l, 16, 0, 0);
}

// ---- fused prep: [0,NCV) convert x->bf16; [NCV,NCV+NT1) transpose in_proj;
//      [NCV+NT1, ...) transpose out_proj. One launch replaces three. ----
#define NCV  ((NROWS * DMODEL / 8 + 255) / 256)              // 2044 blocks
#define NT1X ((DINPROJ + 63) / 64)                           // 35
#define NT1  (NT1X * ((DMODEL + 63) / 64))                   // 35*8 = 280
#define NT2X ((DMODEL + 63) / 64)                            // 8
#define NT2  (NT2X * ((DINNER + 63) / 64))                   // 8*16 = 128

__device__ void transpose_cvt_body(const float* __restrict__ in, short* __restrict__ out,
                                   int R, int Cc, int ldi, int bxv, int byv, int tid,
                                   float (*tile)[65]) {
    const int bx = bxv * 64, by = byv * 64;
#pragma unroll
    for (int i = 0; i < 16; i++) {
        int idx = tid + i * 256; int r = idx >> 6, c = idx & 63;
        float v = 0.f;
        if (by + r < R && bx + c < Cc) v = in[(size_t)(by + r) * ldi + bx + c];
        tile[r][c] = v;
    }
    __syncthreads();
#pragma unroll
    for (int i = 0; i < 16; i++) {
        int idx = tid + i * 256; int c = idx >> 6, r = idx & 63;
        if (bx + c < Cc && by + r < R)
            out[(size_t)(bx + c) * R + by + r] = f2bf(tile[r][c]);
    }
}

__global__ __launch_bounds__(256) void prep_kernel(const float* __restrict__ x,
                                                   const float* __restrict__ in_proj_w,
                                                   const float* __restrict__ out_proj_w,
                                                   short* __restrict__ xb,
                                                   short* __restrict__ w1t,
                                                   short* __restrict__ w2t) {
    __shared__ float tile[64][65];
    const int bid = blockIdx.x;
    const int tid = threadIdx.x;
    if (bid < NCV) {
        int i = bid * 256 + tid;
        if (i < NROWS * DMODEL / 8) {
            float4 v0 = *((const float4*)x + i * 2);
            float4 v1 = *((const float4*)x + i * 2 + 1);
            short t[8];
            t[0]=f2bf(v0.x); t[1]=f2bf(v0.y); t[2]=f2bf(v0.z); t[3]=f2bf(v0.w);
            t[4]=f2bf(v1.x); t[5]=f2bf(v1.y); t[6]=f2bf(v1.z); t[7]=f2bf(v1.w);
            *((bf16x8*)xb + i) = *(const bf16x8*)t;
        }
    } else if (bid < NCV + NT1) {
        int r = bid - NCV;
        transpose_cvt_body(in_proj_w, w1t, DMODEL, DINPROJ, DINPROJ,
                           r % NT1X, r / NT1X, tid, tile);
    } else {
        int r = bid - NCV - NT1;
        transpose_cvt_body(out_proj_w, w2t, DINNER, DMODEL, DMODEL,
                           r % NT2X, r / NT2X, tid, tile);
    }
}

// ---- bf16 MFMA GEMM, 64x64 tile, BK=64, single-buffer gload_lds + XOR swizzle ----
// (R10/R14/R16's proven geometry: 16KB LDS, ~8 blocks/CU.)
// Grid: x walks N (fast), y walks M -> consecutive blocks share the A panel (L2 reuse).
template<bool BF16OUT>
__global__ __launch_bounds__(256) void gemm_bf16(const short* __restrict__ A,
                                                 const short* __restrict__ Bt,
                                                 void* __restrict__ Cv,
                                                 int M, int N, int K,
                                                 int Nbf, float* __restrict__ dtout,
                                                 const float* __restrict__ dt_bias,
                                                 const float* __restrict__ A_log) {
    __shared__ short As[64][64];
    __shared__ short Bs[64][64];
    const int tid = threadIdx.x;
    const int wave = tid >> 6, lane = tid & 63;
    const int bm = blockIdx.y * 64, bn = blockIdx.x * 64;   // swapped: x=N fast, y=M
    const int lane15 = lane & 15;
    const int kgrp = lane >> 4;
    const int srow = lane >> 3;
    const int scol = (lane & 7) ^ srow;
    const int r7 = lane15 & 7;

    f32x4 acc[4];
#pragma unroll
    for (int j = 0; j < 4; j++) acc[j] = (f32x4){0.f, 0.f, 0.f, 0.f};

    const short* Ab = A + (size_t)(bm + wave * 16 + srow) * K + scol * 8;
    const short* Bb = Bt + (size_t)(bn + wave * 16 + srow) * K + scol * 8;

    for (int kk = 0; kk < K; kk += 64) {
        gload16(Ab + kk,                 &As[wave * 16][0]);
        gload16(Ab + 8 * (size_t)K + kk, &As[wave * 16 + 8][0]);
        gload16(Bb + kk,                 &Bs[wave * 16][0]);
        gload16(Bb + 8 * (size_t)K + kk, &Bs[wave * 16 + 8][0]);
        __syncthreads();
        const int arow = (wave << 4) + lane15;
        bf16x8 a0 = *(const bf16x8*)&As[arow][(kgrp ^ r7) * 8];
        bf16x8 a1 = *(const bf16x8*)&As[arow][((kgrp + 4) ^ r7) * 8];
#pragma unroll
        for (int j = 0; j < 4; j++) {
            const int brow = (j << 4) + lane15;
            bf16x8 b0 = *(const bf16x8*)&Bs[brow][(kgrp ^ r7) * 8];
            bf16x8 b1 = *(const bf16x8*)&Bs[brow][((kgrp + 4) ^ r7) * 8];
            acc[j] = MFMA(a0, b0, acc[j]);
            acc[j] = MFMA(a1, b1, acc[j]);
        }
        __syncthreads();
    }
    const int crow = bm + (wave << 4) + ((lane >> 4) << 2);
    const int ccol0 = bn + lane15;
    const bool has_dt = BF16OUT && (dtout != nullptr) && (bn + 64 > Nbf);
    if (!has_dt) {
#pragma unroll
        for (int j = 0; j < 4; j++) {
            int gn = ccol0 + j * 16;
            if (gn >= N) continue;
#pragma unroll
            for (int i = 0; i < 4; i++) {
                int gm = crow + i;
                if (gm >= M) continue;
                float v = acc[j][i];
                if (BF16OUT) ((short*)Cv)[(size_t)gm * Nbf + gn] = f2bf(v);
                else         ((float*)Cv)[(size_t)gm * N + gn] = v;
            }
        }
    } else {
        const int ndt = N - Nbf;
#pragma unroll
        for (int j = 0; j < 4; j++) {
            int gn = ccol0 + j * 16;
            if (gn >= N) continue;
#pragma unroll
            for (int i = 0; i < 4; i++) {
                int gm = crow + i;
                if (gm >= M) continue;
                float v = acc[j][i];
                if (gn >= Nbf) {
                    int h = gn - Nbf;
                    float v2 = v + dt_bias[h];
                    float sp = (v2 > 20.f) ? v2 : log1pf(expf(v2));
                    dtout[(size_t)gm * ndt + h] = sp * (-expf(A_log[h]));
                } else {
                    ((short*)Cv)[(size_t)gm * Nbf + gn] = f2bf(v);
                }
            }
        }
    }
}

// -------- depthwise causal conv (k=4) + bias + SiLU; 2 channels/thread, grid-stride --------
__global__ __launch_bounds__(256) void conv_silu_kernel(const short* __restrict__ zxb,
                                                        const float* __restrict__ conv_w,
                                                        const float* __restrict__ conv_b,
                                                        short* __restrict__ convo) {
    const int CH2 = CONVDIM / 2;   // 576 channel pairs
    const int total = BATCH * (SEQ/4) * CH2;
    for (int idx = blockIdx.x * 256 + threadIdx.x; idx < total; idx += gridDim.x * 256) {
        int cpair = idx % CH2;
        int q = idx / CH2;
        int b = q / (SEQ/4);
        int t0 = (q % (SEQ/4)) * 4;
        int c = cpair * 2;
        const size_t base = ((size_t)b * SEQ + t0) * ZW + DINNER + c;
        float4 wv0 = *(const float4*)&conv_w[c * 4];
        float4 wv1 = *(const float4*)&conv_w[c * 4 + 4];
        float x0[7], x1[7];
#pragma unroll
        for (int i = 0; i < 7; i++) {
            int t = t0 - 3 + i;
            if (t >= 0) {
                unsigned u = *(const unsigned*)&zxb[base + (size_t)(i - 3) * ZW];
                x0[i] = bf2f_lo(u); x1[i] = bf2f_hi(u);
            } else { x0[i] = 0.f; x1[i] = 0.f; }
        }
        const float b0 = conv_b[c], b1 = conv_b[c + 1];
        const size_t obase = ((size_t)b * SEQ + t0) * CONVDIM + c;
#pragma unroll
        for (int i = 0; i < 4; i++) {
            float a0 = b0 + x0[i]*wv0.x + x0[i+1]*wv0.y + x0[i+2]*wv0.z + x0[i+3]*wv0.w;
            float a1 = b1 + x1[i]*wv1.x + x1[i+1]*wv1.y + x1[i+2]*wv1.z + x1[i+3]*wv1.w;
            float s0 = a0 / (1.f + expf(-a0));
            float s1 = a1 / (1.f + expf(-a1));
            unsigned o = (unsigned)(unsigned short)f2bf(s0) |
                         ((unsigned)(unsigned short)f2bf(s1) << 16);
            *(unsigned*)&convo[obase + (size_t)i * CONVDIM] = o;
        }
    }
}

// ------------- Phase A: per-(b,chunk,head) chunk state S = (w x)^T B (bf16 out) -------------
__global__ __launch_bounds__(256) void chunk_state_kernel(
    const short* __restrict__ convo,
    const float* __restrict__ lab,
    const float* __restrict__ A_log,
    short* __restrict__ Sbf,
    float* __restrict__ atot)
{
    const int blk = blockIdx.x;
    const int h  = blk & 15;
    const int bc = blk >> 4;
    const int c  = bc & (NCHUNK - 1);
    const int b  = bc >> 5;
    const int t0 = c * Q;
    const int len = min(Q, SEQ - t0);
    const int tid = threadIdx.x;
    const int wave = tid >> 6, lane = tid & 63;
    const size_t rowbase = (size_t)b * SEQ + t0;

    __shared__ short Xt[64][72];    // x^T    [p][s]
    __shared__ short Bw[64][72];    // (w*B)^T [n][s]
    __shared__ float sw[64];

    if (tid < 64) {
        const float nAinv = -expf(-A_log[h]);
        float lav = 0.f;
        if (tid < len) lav = lab[(rowbase + tid) * NHEADS + h];
        float dtv = lav * nAinv;
        float v = lav;
#pragma unroll
        for (int off = 1; off < 64; off <<= 1) {
            float nb = __shfl_up(v, off);
            if (lane >= off) v += nb;
        }
        float last = __shfl(v, 63);
        sw[tid] = expf(last - v) * dtv;
        if (tid == 63) atot[blk] = expf(last);
    }
    __syncthreads();

    {
        const int r = tid >> 2, qq = tid & 3;
        const bf16x8 zz = {0,0,0,0,0,0,0,0};
        bf16x8 b0 = zz, b1 = zz, x0 = zz, x1 = zz;
        if (r < len) {
            const short* row = convo + (rowbase + r) * CONVDIM;
            b0 = *(const bf16x8*)&row[1024 + qq*16];
            b1 = *(const bf16x8*)&row[1024 + qq*16 + 8];
            x0 = *(const bf16x8*)&row[h*64 + qq*16];
            x1 = *(const bf16x8*)&row[h*64 + qq*16 + 8];
        }
        const float wsc = sw[r];
        short bs[16], xs[16];
        *(bf16x8*)&bs[0] = b0; *(bf16x8*)&bs[8] = b1;
        *(bf16x8*)&xs[0] = x0; *(bf16x8*)&xs[8] = x1;
#pragma unroll
        for (int i = 0; i < 16; i++) Xt[qq*16+i][r] = xs[i];
#pragma unroll
        for (int i = 0; i < 16; i++) Bw[qq*16+i][r] = f2bf(bf2f(bs[i]) * wsc);
    }
    __syncthreads();

    const int arow = (wave << 4) + (lane & 15);
    const int koff = (lane >> 4) << 3;
    const int trow0 = (wave << 4) + ((lane >> 4) << 2);
    const int scol = lane & 15;

    f32x4 sacc[4];
#pragma unroll
    for (int j = 0; j < 4; j++) sacc[j] = (f32x4){0.f,0.f,0.f,0.f};
    {
        bf16x8 a0 = *(const bf16x8*)&Xt[arow][koff];
        bf16x8 a1 = *(const bf16x8*)&Xt[arow][32 + koff];
#pragma unroll
        for (int j = 0; j < 4; j++) {
            const int brow = (j << 4) + (lane & 15);
            bf16x8 b0 = *(const bf16x8*)&Bw[brow][koff];
            bf16x8 b1 = *(const bf16x8*)&Bw[brow][32 + koff];
            sacc[j] = MFMA(a0, b0, sacc[j]);
            sacc[j] = MFMA(a1, b1, sacc[j]);
        }
    }
    const size_t sbase = (size_t)blk * 4096;
#pragma unroll
    for (int j = 0; j < 4; j++) {
        int n = j * 16 + scol;
#pragma unroll
        for (int i = 0; i < 4; i++) {
            int p = trow0 + i;
            Sbf[sbase + p * 64 + n] = f2bf(sacc[j][i]);
        }
    }
}

// ------- Phase B: scan over bf16 chunk states; 2 elements/thread, 4B access -------
__global__ __launch_bounds__(256) void chunk_state_scan_kernel(
    const short* __restrict__ Sbf, const float* __restrict__ atot,
    short* __restrict__ Hbf)
{
    int e = blockIdx.x * 256 + threadIdx.x;       // 64*2048 element-pairs
    int bh = e >> 11;
    int el = (e & 2047) * 2;
    int b = bh >> 4, h = bh & 15;
    float H0 = 0.f, H1 = 0.f;
    for (int c = 0; c < NCHUNK; c++) {
        int blk = (b * NCHUNK + c) * NHEADS + h;
        size_t off = (size_t)blk * 4096 + el;
        unsigned sv = *(const unsigned*)&Sbf[off];
        unsigned hv = (unsigned)(unsigned short)f2bf(H0) |
                      ((unsigned)(unsigned short)f2bf(H1) << 16);
        *(unsigned*)&Hbf[off] = hv;
        float at = atot[blk];
        H0 = at * H0 + bf2f_lo(sv);
        H1 = at * H1 + bf2f_hi(sv);
    }
}

// ------- Phase C: Y = (E_masked @ X) + exp(cum_t)*(C @ Hprev^T) + D*x -> bf16 -------
// H fragments in registers (one-time pre-barrier load; R17/R18-validated), no Hs LDS tile.
__global__ __launch_bounds__(256) void chunk_yfuse_kernel(
    const short* __restrict__ convo,
    const float* __restrict__ lab,
    const float* __restrict__ A_log,
    const float* __restrict__ D_skip,
    const short* __restrict__ Hbf,
    short* __restrict__ ybf)
{
    const int blk = blockIdx.x;
    const int h  = blk & 15;
    const int bc = blk >> 4;
    const int c  = bc & (NCHUNK - 1);
    const int b  = bc >> 5;
    const int t0 = c * Q;
    const int len = min(Q, SEQ - t0);
    const int tid = threadIdx.x;
    const int wave = tid >> 6, lane = tid & 63;
    const size_t rowbase = (size_t)b * SEQ + t0;

    __shared__ short Ct[64][72];    // C [t][n]; reused as E [t][s]
    __shared__ short Bt2[64][72];   // B [s][n]
    __shared__ short Xt[64][72];    // x^T [p][s]
    __shared__ float cum[64], sdt[64];

    const int lane15 = lane & 15;
    const int koff = (lane >> 4) << 3;

    if (tid < 64) {
        const float nAinv = -expf(-A_log[h]);
        float lav = 0.f;
        if (tid < len) lav = lab[(rowbase + tid) * NHEADS + h];
        float dtv = lav * nAinv;
        float v = lav;
#pragma unroll
        for (int off = 1; off < 64; off <<= 1) {
            float nb = __shfl_up(v, off);
            if (lane >= off) v += nb;
        }
        cum[tid] = v; sdt[tid] = dtv;
    }

    // H fragments straight to registers (one-time load, consumed after barrier)
    bf16x8 hf0[4], hf1[4];
    {
        const size_t hbase = (size_t)blk * 4096;
#pragma unroll
        for (int j = 0; j < 4; j++) {
            int brow = (j << 4) + lane15;
            hf0[j] = *(const bf16x8*)&Hbf[hbase + brow * 64 + koff];
            hf1[j] = *(const bf16x8*)&Hbf[hbase + brow * 64 + koff + 32];
        }
    }

    {
        const int r = tid >> 2, qq = tid & 3;
        const bf16x8 zz = {0,0,0,0,0,0,0,0};
        bf16x8 c0 = zz, c1 = zz, b0 = zz, b1 = zz, x0 = zz, x1 = zz;
        if (r < len) {
            const short* row = convo + (rowbase + r) * CONVDIM;
            c0 = *(const bf16x8*)&row[1088 + qq*16];
            c1 = *(const bf16x8*)&row[1088 + qq*16 + 8];
            b0 = *(const bf16x8*)&row[1024 + qq*16];
            b1 = *(const bf16x8*)&row[1024 + qq*16 + 8];
            x0 = *(const bf16x8*)&row[h*64 + qq*16];
            x1 = *(const bf16x8*)&row[h*64 + qq*16 + 8];
        }
        *(bf16x8*)&Ct[r][qq*16]    = c0; *(bf16x8*)&Ct[r][qq*16+8]  = c1;
        *(bf16x8*)&Bt2[r][qq*16]   = b0; *(bf16x8*)&Bt2[r][qq*16+8] = b1;
        short xs[16];
        *(bf16x8*)&xs[0] = x0; *(bf16x8*)&xs[8] = x1;
#pragma unroll
        for (int i = 0; i < 16; i++) Xt[qq*16+i][r] = xs[i];
    }
    __syncthreads();

    const int arow = (wave << 4) + lane15;
    const int trow0 = (wave << 4) + ((lane >> 4) << 2);
    const int scol = lane15;

    // E = C.B^T and I = C.H^T (H from registers)
    f32x4 eacc[4], iacc[4];
#pragma unroll
    for (int j = 0; j < 4; j++) { eacc[j] = (f32x4){0.f,0.f,0.f,0.f}; iacc[j] = (f32x4){0.f,0.f,0.f,0.f}; }
    {
        bf16x8 a0 = *(const bf16x8*)&Ct[arow][koff];
        bf16x8 a1 = *(const bf16x8*)&Ct[arow][32 + koff];
#pragma unroll
        for (int j = 0; j < 4; j++) {
            const int brow = (j << 4) + lane15;
            bf16x8 b0 = *(const bf16x8*)&Bt2[brow][koff];
            bf16x8 b1 = *(const bf16x8*)&Bt2[brow][32 + koff];
            eacc[j] = MFMA(a0, b0, eacc[j]);
            eacc[j] = MFMA(a1, b1, eacc[j]);
            iacc[j] = MFMA(a0, hf0[j], iacc[j]);
            iacc[j] = MFMA(a1, hf1[j], iacc[j]);
        }
    }
    short ebf[4][4];
#pragma unroll
    for (int j = 0; j < 4; j++) {
        int s = j * 16 + scol;
#pragma unroll
        for (int i = 0; i < 4; i++) {
            int t = trow0 + i;
            float val = 0.f;
            if (s <= t) val = eacc[j][i] * expf(cum[t] - cum[s]) * sdt[s];
            ebf[j][i] = f2bf(val);
        }
    }
    __syncthreads();
#pragma unroll
    for (int j = 0; j < 4; j++)
#pragma unroll
        for (int i = 0; i < 4; i++)
            Ct[trow0 + i][j * 16 + scol] = ebf[j][i];
    __syncthreads();

    // Y_intra = E @ X
    f32x4 yacc[4];
#pragma unroll
    for (int j = 0; j < 4; j++) yacc[j] = (f32x4){0.f,0.f,0.f,0.f};
    {
        bf16x8 a0 = *(const bf16x8*)&Ct[arow][koff];
        bf16x8 a1 = *(const bf16x8*)&Ct[arow][32 + koff];
#pragma unroll
        for (int j = 0; j < 4; j++) {
            const int brow = (j << 4) + lane15;
            bf16x8 b0 = *(const bf16x8*)&Xt[brow][koff];
            bf16x8 b1 = *(const bf16x8*)&Xt[brow][32 + koff];
            yacc[j] = MFMA(a0, b0, yacc[j]);
            yacc[j] = MFMA(a1, b1, yacc[j]);
        }
    }
    const float dsk = D_skip[h];
#pragma unroll
    for (int j = 0; j < 4; j++) {
        int p = j * 16 + scol;
#pragma unroll
        for (int i = 0; i < 4; i++) {
            int t = trow0 + i;
            if (t < len) {
                float ce = expf(cum[t]);
                float xv = bf2f(Xt[p][t]);
                float val = yacc[j][i] + ce * iacc[j][i] + dsk * xv;
                ybf[(rowbase + t) * DINNER + h * 64 + p] = f2bf(val);
            }
        }
    }
}

// ------------- gate with silu(z) + RMSNorm; vectorized short4 access -------------
__global__ __launch_bounds__(256) void gate_rmsnorm_kernel(short* __restrict__ y,
                                                           const short* __restrict__ zxb,
                                                           const float* __restrict__ norm_w) {
    const int m = blockIdx.x;
    const int tid = threadIdx.x;
    const int c = tid * 4;
    short4v yv = *(const short4v*)&y[(size_t)m * DINNER + c];
    short4v zv = *(const short4v*)&zxb[(size_t)m * ZW + c];
    float vals[4];
    float ss = 0.f;
#pragma unroll
    for (int i = 0; i < 4; i++) {
        float v = bf2f(yv[i]);
        float z = bf2f(zv[i]);
        float g = v * (z / (1.f + expf(-z)));
        vals[i] = g;
        ss += g * g;
    }
#pragma unroll
    for (int mask = 1; mask < 64; mask <<= 1) ss += __shfl_xor(ss, mask);
    __shared__ float red[4];
    if ((tid & 63) == 0) red[tid >> 6] = ss;
    __syncthreads();
    float tot = red[0] + red[1] + red[2] + red[3];
    float scale = rsqrtf(tot / 1024.f + 1e-5f);
    short4v ov;
#pragma unroll
    for (int i = 0; i < 4; i++) ov[i] = f2bf(vals[i] * scale * norm_w[c + i]);
    *(short4v*)&y[(size_t)m * DINNER + c] = ov;
}

extern "C" void kernel_launch(void* const* d_in, const int* in_sizes, int n_in,
                              void* d_out, int out_size, void* d_ws, size_t ws_size,
                              hipStream_t stream) {
    const float* x          = (const float*)d_in[0];
    const float* in_proj_w  = (const float*)d_in[1];
    const float* conv_w     = (const float*)d_in[2];
    const float* conv_b     = (const float*)d_in[3];
    const float* dt_bias    = (const float*)d_in[4];
    const float* A_log      = (const float*)d_in[5];
    const float* D_skip     = (const float*)d_in[6];
    const float* norm_w     = (const float*)d_in[7];
    const float* out_proj_w = (const float*)d_in[8];
    float* out = (float*)d_out;

    short* zxb   = (short*)d_ws;                              // NROWS*ZW bf16
    short* convo = zxb + (size_t)NROWS * ZW;                  // NROWS*CONVDIM bf16
    short* ybf   = convo + (size_t)NROWS * CONVDIM;           // NROWS*1024 bf16
    short* Hbf   = ybf + (size_t)NROWS * DINNER;              // 2048*4096 bf16
    short* Sbf   = Hbf + (size_t)2048 * 4096;                 // 2048*4096 bf16
    float* lab   = (float*)(Sbf + (size_t)2048 * 4096);       // NROWS*16 f32
    float* atotb = lab + (size_t)NROWS * NHEADS;              // 2048 f32
    short* w2t   = (short*)(atotb + 2048);                    // [512][1024] bf16
    // transient aliases (dead before hosts written):
    short* xb  = convo;                                       // NROWS*512 bf16, dead after K1
    short* w1t = xb + (size_t)NROWS * DMODEL;                 // 2192*512 bf16, dead after K1

    // prep: one fused launch (convert + both weight transposes)
    prep_kernel<<<NCV + NT1 + NT2, 256, 0, stream>>>(x, in_proj_w, out_proj_w, xb, w1t, w2t);

    // K1: in_proj GEMM (64x64, gload_lds, N-fast grid); cols <2176 -> bf16 zxb, >=2176 -> la
    {
        dim3 g((DINPROJ + 63) / 64, (NROWS + 63) / 64);       // 35 x 128 (x=N, y=M)
        gemm_bf16<true><<<g, 256, 0, stream>>>(xb, w1t, zxb, NROWS, DINPROJ, DMODEL,
                                               ZW, lab, dt_bias, A_log);
    }

    // K2: conv + silu (bf16 in/out, 2 channels/thread, grid-stride)
    conv_silu_kernel<<<2048, 256, 0, stream>>>(zxb, conv_w, conv_b, convo);

    // K3a: chunk states (bf16)
    chunk_state_kernel<<<BATCH * NCHUNK * NHEADS, 256, 0, stream>>>(
        convo, lab, A_log, Sbf, atotb);

    // K3b: inter-chunk recurrence -> bf16 Hprev (2 elems/thread)
    chunk_state_scan_kernel<<<(64 * 2048) / 256, 256, 0, stream>>>(Sbf, atotb, Hbf);

    // K3c: fused intra + inter + D-skip -> bf16 y (H in registers)
    chunk_yfuse_kernel<<<BATCH * NCHUNK * NHEADS, 256, 0, stream>>>(
        convo, lab, A_log, D_skip, Hbf, ybf);

    // K4: gate + rmsnorm (in place, bf16, vectorized)
    gate_rmsnorm_kernel<<<NROWS, 256, 0, stream>>>(ybf, zxb, norm_w);

    // K5: out = ybf @ out_proj_w (64x64, gload_lds, N-fast grid)
    {
        dim3 g((DMODEL + 63) / 64, (NROWS + 63) / 64);        // 8 x 128 (x=N, y=M)
        gemm_bf16<false><<<g, 256, 0, stream>>>(ybf, w2t, out, NROWS, DMODEL, DINNER,
                                                DMODEL, nullptr, nullptr, nullptr);
    }
}

// Round 21
// 129.205 us; speedup vs baseline: 1.0574x; 1.0574x over previous
//
#include <hip/hip_runtime.h>
#include <hip/hip_bf16.h>
#include <math.h>
#include <string.h>

#define BATCH   4
#define SEQ     2044
#define DMODEL  512
#define DINNER  1024
#define NHEADS  16
#define HEADDIM 64
#define DSTATE  64
#define CONVDIM 1152
#define DINPROJ 2192
#define ZW      2176          // bf16-stored width of zxbcdt (z + xBC); dt cols -> fp32 lab
#define NROWS   (BATCH*SEQ)   // 8176
#define Q       64
#define NCHUNK  32

typedef __attribute__((ext_vector_type(8))) short bf16x8;
typedef __attribute__((ext_vector_type(4))) short short4v;
typedef __attribute__((ext_vector_type(4))) float f32x4;

#define MFMA(a,b,c) __builtin_amdgcn_mfma_f32_16x16x32_bf16((a),(b),(c),0,0,0)

__device__ inline short f2bf(float f) {
    __hip_bfloat16 h = __float2bfloat16(f);
    short s; memcpy(&s, &h, 2); return s;
}
__device__ inline float bf2f(short s) {
    unsigned u = ((unsigned)(unsigned short)s) << 16;
    float f; memcpy(&f, &u, 4); return f;
}
__device__ inline float bf2f_lo(unsigned u) {
    unsigned v = u << 16; float f; memcpy(&f, &v, 4); return f;
}
__device__ inline float bf2f_hi(unsigned u) {
    unsigned v = u & 0xffff0000u; float f; memcpy(&f, &v, 4); return f;
}

// async global->LDS, 16B per lane; LDS dest = wave-uniform base + lane*16
__device__ __forceinline__ void gload16(const short* g, short* l) {
    __builtin_amdgcn_global_load_lds(
        (const __attribute__((address_space(1))) void*)g,
        (__attribute__((address_space(3))) void*)l, 16, 0, 0);
}

// ---- fused prep: [0,NCV) convert x->bf16; [NCV,NCV+NT1) transpose in_proj;
//      [NCV+NT1, ...) transpose out_proj. One launch replaces three. ----
#define NCV  ((NROWS * DMODEL / 8 + 255) / 256)              // 2044 blocks
#define NT1X ((DINPROJ + 63) / 64)                           // 35
#define NT1  (NT1X * ((DMODEL + 63) / 64))                   // 35*8 = 280
#define NT2X ((DMODEL + 63) / 64)                            // 8
#define NT2  (NT2X * ((DINNER + 63) / 64))                   // 8*16 = 128

__device__ void transpose_cvt_body(const float* __restrict__ in, short* __restrict__ out,
                                   int R, int Cc, int ldi, int bxv, int byv, int tid,
                                   float (*tile)[65]) {
    const int bx = bxv * 64, by = byv * 64;
#pragma unroll
    for (int i = 0; i < 16; i++) {
        int idx = tid + i * 256; int r = idx >> 6, c = idx & 63;
        float v = 0.f;
        if (by + r < R && bx + c < Cc) v = in[(size_t)(by + r) * ldi + bx + c];
        tile[r][c] = v;
    }
    __syncthreads();
#pragma unroll
    for (int i = 0; i < 16; i++) {
        int idx = tid + i * 256; int c = idx >> 6, r = idx & 63;
        if (bx + c < Cc && by + r < R)
            out[(size_t)(bx + c) * R + by + r] = f2bf(tile[r][c]);
    }
}

__global__ __launch_bounds__(256) void prep_kernel(const float* __restrict__ x,
                                                   const float* __restrict__ in_proj_w,
                                                   const float* __restrict__ out_proj_w,
                                                   short* __restrict__ xb,
                                                   short* __restrict__ w1t,
                                                   short* __restrict__ w2t) {
    __shared__ float tile[64][65];
    const int bid = blockIdx.x;
    const int tid = threadIdx.x;
    if (bid < NCV) {
        int i = bid * 256 + tid;
        if (i < NROWS * DMODEL / 8) {
            float4 v0 = *((const float4*)x + i * 2);
            float4 v1 = *((const float4*)x + i * 2 + 1);
            short t[8];
            t[0]=f2bf(v0.x); t[1]=f2bf(v0.y); t[2]=f2bf(v0.z); t[3]=f2bf(v0.w);
            t[4]=f2bf(v1.x); t[5]=f2bf(v1.y); t[6]=f2bf(v1.z); t[7]=f2bf(v1.w);
            *((bf16x8*)xb + i) = *(const bf16x8*)t;
        }
    } else if (bid < NCV + NT1) {
        int r = bid - NCV;
        transpose_cvt_body(in_proj_w, w1t, DMODEL, DINPROJ, DINPROJ,
                           r % NT1X, r / NT1X, tid, tile);
    } else {
        int r = bid - NCV - NT1;
        transpose_cvt_body(out_proj_w, w2t, DINNER, DMODEL, DMODEL,
                           r % NT2X, r / NT2X, tid, tile);
    }
}

// ---- bf16 MFMA GEMM, 64x64 tile, BK=64, single-buffer gload_lds + XOR swizzle ----
// (R10/R14/R16/R19's proven geometry: 16KB LDS, ~8 blocks/CU, M-fast grid.)
template<bool BF16OUT>
__global__ __launch_bounds__(256) void gemm_bf16(const short* __restrict__ A,
                                                 const short* __restrict__ Bt,
                                                 void* __restrict__ Cv,
                                                 int M, int N, int K,
                                                 int Nbf, float* __restrict__ dtout,
                                                 const float* __restrict__ dt_bias,
                                                 const float* __restrict__ A_log) {
    __shared__ short As[64][64];
    __shared__ short Bs[64][64];
    const int tid = threadIdx.x;
    const int wave = tid >> 6, lane = tid & 63;
    const int bm = blockIdx.x * 64, bn = blockIdx.y * 64;
    const int lane15 = lane & 15;
    const int kgrp = lane >> 4;
    const int srow = lane >> 3;
    const int scol = (lane & 7) ^ srow;
    const int r7 = lane15 & 7;

    f32x4 acc[4];
#pragma unroll
    for (int j = 0; j < 4; j++) acc[j] = (f32x4){0.f, 0.f, 0.f, 0.f};

    const short* Ab = A + (size_t)(bm + wave * 16 + srow) * K + scol * 8;
    const short* Bb = Bt + (size_t)(bn + wave * 16 + srow) * K + scol * 8;

    for (int kk = 0; kk < K; kk += 64) {
        gload16(Ab + kk,                 &As[wave * 16][0]);
        gload16(Ab + 8 * (size_t)K + kk, &As[wave * 16 + 8][0]);
        gload16(Bb + kk,                 &Bs[wave * 16][0]);
        gload16(Bb + 8 * (size_t)K + kk, &Bs[wave * 16 + 8][0]);
        __syncthreads();
        const int arow = (wave << 4) + lane15;
        bf16x8 a0 = *(const bf16x8*)&As[arow][(kgrp ^ r7) * 8];
        bf16x8 a1 = *(const bf16x8*)&As[arow][((kgrp + 4) ^ r7) * 8];
#pragma unroll
        for (int j = 0; j < 4; j++) {
            const int brow = (j << 4) + lane15;
            bf16x8 b0 = *(const bf16x8*)&Bs[brow][(kgrp ^ r7) * 8];
            bf16x8 b1 = *(const bf16x8*)&Bs[brow][((kgrp + 4) ^ r7) * 8];
            acc[j] = MFMA(a0, b0, acc[j]);
            acc[j] = MFMA(a1, b1, acc[j]);
        }
        __syncthreads();
    }
    const int crow = bm + (wave << 4) + ((lane >> 4) << 2);
    const int ccol0 = bn + lane15;
    const bool has_dt = BF16OUT && (dtout != nullptr) && (bn + 64 > Nbf);
    if (!has_dt) {
#pragma unroll
        for (int j = 0; j < 4; j++) {
            int gn = ccol0 + j * 16;
            if (gn >= N) continue;
#pragma unroll
            for (int i = 0; i < 4; i++) {
                int gm = crow + i;
                if (gm >= M) continue;
                float v = acc[j][i];
                if (BF16OUT) ((short*)Cv)[(size_t)gm * Nbf + gn] = f2bf(v);
                else         ((float*)Cv)[(size_t)gm * N + gn] = v;
            }
        }
    } else {
        const int ndt = N - Nbf;
#pragma unroll
        for (int j = 0; j < 4; j++) {
            int gn = ccol0 + j * 16;
            if (gn >= N) continue;
#pragma unroll
            for (int i = 0; i < 4; i++) {
                int gm = crow + i;
                if (gm >= M) continue;
                float v = acc[j][i];
                if (gn >= Nbf) {
                    int h = gn - Nbf;
                    float v2 = v + dt_bias[h];
                    float sp = (v2 > 20.f) ? v2 : log1pf(expf(v2));
                    dtout[(size_t)gm * ndt + h] = sp * (-expf(A_log[h]));
                } else {
                    ((short*)Cv)[(size_t)gm * Nbf + gn] = f2bf(v);
                }
            }
        }
    }
}

// -------- depthwise causal conv (k=4) + bias + SiLU; 2 channels/thread, grid-stride --------
__global__ __launch_bounds__(256) void conv_silu_kernel(const short* __restrict__ zxb,
                                                        const float* __restrict__ conv_w,
                                                        const float* __restrict__ conv_b,
                                                        short* __restrict__ convo) {
    const int CH2 = CONVDIM / 2;   // 576 channel pairs
    const int total = BATCH * (SEQ/4) * CH2;
    for (int idx = blockIdx.x * 256 + threadIdx.x; idx < total; idx += gridDim.x * 256) {
        int cpair = idx % CH2;
        int q = idx / CH2;
        int b = q / (SEQ/4);
        int t0 = (q % (SEQ/4)) * 4;
        int c = cpair * 2;
        const size_t base = ((size_t)b * SEQ + t0) * ZW + DINNER + c;
        float4 wv0 = *(const float4*)&conv_w[c * 4];
        float4 wv1 = *(const float4*)&conv_w[c * 4 + 4];
        float x0[7], x1[7];
#pragma unroll
        for (int i = 0; i < 7; i++) {
            int t = t0 - 3 + i;
            if (t >= 0) {
                unsigned u = *(const unsigned*)&zxb[base + (size_t)(i - 3) * ZW];
                x0[i] = bf2f_lo(u); x1[i] = bf2f_hi(u);
            } else { x0[i] = 0.f; x1[i] = 0.f; }
        }
        const float b0 = conv_b[c], b1 = conv_b[c + 1];
        const size_t obase = ((size_t)b * SEQ + t0) * CONVDIM + c;
#pragma unroll
        for (int i = 0; i < 4; i++) {
            float a0 = b0 + x0[i]*wv0.x + x0[i+1]*wv0.y + x0[i+2]*wv0.z + x0[i+3]*wv0.w;
            float a1 = b1 + x1[i]*wv1.x + x1[i+1]*wv1.y + x1[i+2]*wv1.z + x1[i+3]*wv1.w;
            float s0 = a0 / (1.f + expf(-a0));
            float s1 = a1 / (1.f + expf(-a1));
            unsigned o = (unsigned)(unsigned short)f2bf(s0) |
                         ((unsigned)(unsigned short)f2bf(s1) << 16);
            *(unsigned*)&convo[obase + (size_t)i * CONVDIM] = o;
        }
    }
}

// ------------- Phase A: per-(b,chunk,head) chunk state S = (w x)^T B (bf16 out) -------------
__global__ __launch_bounds__(256) void chunk_state_kernel(
    const short* __restrict__ convo,
    const float* __restrict__ lab,
    const float* __restrict__ A_log,
    short* __restrict__ Sbf,
    float* __restrict__ atot)
{
    const int blk = blockIdx.x;
    const int h  = blk & 15;
    const int bc = blk >> 4;
    const int c  = bc & (NCHUNK - 1);
    const int b  = bc >> 5;
    const int t0 = c * Q;
    const int len = min(Q, SEQ - t0);
    const int tid = threadIdx.x;
    const int wave = tid >> 6, lane = tid & 63;
    const size_t rowbase = (size_t)b * SEQ + t0;

    __shared__ short Xt[64][72];    // x^T    [p][s]
    __shared__ short Bw[64][72];    // (w*B)^T [n][s]
    __shared__ float sw[64];

    if (tid < 64) {
        const float nAinv = -expf(-A_log[h]);
        float lav = 0.f;
        if (tid < len) lav = lab[(rowbase + tid) * NHEADS + h];
        float dtv = lav * nAinv;
        float v = lav;
#pragma unroll
        for (int off = 1; off < 64; off <<= 1) {
            float nb = __shfl_up(v, off);
            if (lane >= off) v += nb;
        }
        float last = __shfl(v, 63);
        sw[tid] = expf(last - v) * dtv;
        if (tid == 63) atot[blk] = expf(last);
    }
    __syncthreads();

    {
        const int r = tid >> 2, qq = tid & 3;
        const bf16x8 zz = {0,0,0,0,0,0,0,0};
        bf16x8 b0 = zz, b1 = zz, x0 = zz, x1 = zz;
        if (r < len) {
            const short* row = convo + (rowbase + r) * CONVDIM;
            b0 = *(const bf16x8*)&row[1024 + qq*16];
            b1 = *(const bf16x8*)&row[1024 + qq*16 + 8];
            x0 = *(const bf16x8*)&row[h*64 + qq*16];
            x1 = *(const bf16x8*)&row[h*64 + qq*16 + 8];
        }
        const float wsc = sw[r];
        short bs[16], xs[16];
        *(bf16x8*)&bs[0] = b0; *(bf16x8*)&bs[8] = b1;
        *(bf16x8*)&xs[0] = x0; *(bf16x8*)&xs[8] = x1;
#pragma unroll
        for (int i = 0; i < 16; i++) Xt[qq*16+i][r] = xs[i];
#pragma unroll
        for (int i = 0; i < 16; i++) Bw[qq*16+i][r] = f2bf(bf2f(bs[i]) * wsc);
    }
    __syncthreads();

    const int arow = (wave << 4) + (lane & 15);
    const int koff = (lane >> 4) << 3;
    const int trow0 = (wave << 4) + ((lane >> 4) << 2);
    const int scol = lane & 15;

    f32x4 sacc[4];
#pragma unroll
    for (int j = 0; j < 4; j++) sacc[j] = (f32x4){0.f,0.f,0.f,0.f};
    {
        bf16x8 a0 = *(const bf16x8*)&Xt[arow][koff];
        bf16x8 a1 = *(const bf16x8*)&Xt[arow][32 + koff];
#pragma unroll
        for (int j = 0; j < 4; j++) {
            const int brow = (j << 4) + (lane & 15);
            bf16x8 b0 = *(const bf16x8*)&Bw[brow][koff];
            bf16x8 b1 = *(const bf16x8*)&Bw[brow][32 + koff];
            sacc[j] = MFMA(a0, b0, sacc[j]);
            sacc[j] = MFMA(a1, b1, sacc[j]);
        }
    }
    const size_t sbase = (size_t)blk * 4096;
#pragma unroll
    for (int j = 0; j < 4; j++) {
        int n = j * 16 + scol;
#pragma unroll
        for (int i = 0; i < 4; i++) {
            int p = trow0 + i;
            Sbf[sbase + p * 64 + n] = f2bf(sacc[j][i]);
        }
    }
}

// ------- Phase B: scan over bf16 chunk states; 2 elements/thread, 4B access -------
__global__ __launch_bounds__(256) void chunk_state_scan_kernel(
    const short* __restrict__ Sbf, const float* __restrict__ atot,
    short* __restrict__ Hbf)
{
    int e = blockIdx.x * 256 + threadIdx.x;       // 64*2048 element-pairs
    int bh = e >> 11;
    int el = (e & 2047) * 2;
    int b = bh >> 4, h = bh & 15;
    float H0 = 0.f, H1 = 0.f;
    for (int c = 0; c < NCHUNK; c++) {
        int blk = (b * NCHUNK + c) * NHEADS + h;
        size_t off = (size_t)blk * 4096 + el;
        unsigned sv = *(const unsigned*)&Sbf[off];
        unsigned hv = (unsigned)(unsigned short)f2bf(H0) |
                      ((unsigned)(unsigned short)f2bf(H1) << 16);
        *(unsigned*)&Hbf[off] = hv;
        float at = atot[blk];
        H0 = at * H0 + bf2f_lo(sv);
        H1 = at * H1 + bf2f_hi(sv);
    }
}

// ------- Phase C: Y = (E_masked @ X) + exp(cum_t)*(C @ Hprev^T) + D*x -> bf16 -------
// H fragments in registers (one-time pre-barrier load; R17/R18-validated), no Hs LDS tile.
__global__ __launch_bounds__(256) void chunk_yfuse_kernel(
    const short* __restrict__ convo,
    const float* __restrict__ lab,
    const float* __restrict__ A_log,
    const float* __restrict__ D_skip,
    const short* __restrict__ Hbf,
    short* __restrict__ ybf)
{
    const int blk = blockIdx.x;
    const int h  = blk & 15;
    const int bc = blk >> 4;
    const int c  = bc & (NCHUNK - 1);
    const int b  = bc >> 5;
    const int t0 = c * Q;
    const int len = min(Q, SEQ - t0);
    const int tid = threadIdx.x;
    const int wave = tid >> 6, lane = tid & 63;
    const size_t rowbase = (size_t)b * SEQ + t0;

    __shared__ short Ct[64][72];    // C [t][n]; reused as E [t][s]
    __shared__ short Bt2[64][72];   // B [s][n]
    __shared__ short Xt[64][72];    // x^T [p][s]
    __shared__ float cum[64], sdt[64];

    const int lane15 = lane & 15;
    const int koff = (lane >> 4) << 3;

    if (tid < 64) {
        const float nAinv = -expf(-A_log[h]);
        float lav = 0.f;
        if (tid < len) lav = lab[(rowbase + tid) * NHEADS + h];
        float dtv = lav * nAinv;
        float v = lav;
#pragma unroll
        for (int off = 1; off < 64; off <<= 1) {
            float nb = __shfl_up(v, off);
            if (lane >= off) v += nb;
        }
        cum[tid] = v; sdt[tid] = dtv;
    }

    // H fragments straight to registers (one-time load, consumed after barrier)
    bf16x8 hf0[4], hf1[4];
    {
        const size_t hbase = (size_t)blk * 4096;
#pragma unroll
        for (int j = 0; j < 4; j++) {
            int brow = (j << 4) + lane15;
            hf0[j] = *(const bf16x8*)&Hbf[hbase + brow * 64 + koff];
            hf1[j] = *(const bf16x8*)&Hbf[hbase + brow * 64 + koff + 32];
        }
    }

    {
        const int r = tid >> 2, qq = tid & 3;
        const bf16x8 zz = {0,0,0,0,0,0,0,0};
        bf16x8 c0 = zz, c1 = zz, b0 = zz, b1 = zz, x0 = zz, x1 = zz;
        if (r < len) {
            const short* row = convo + (rowbase + r) * CONVDIM;
            c0 = *(const bf16x8*)&row[1088 + qq*16];
            c1 = *(const bf16x8*)&row[1088 + qq*16 + 8];
            b0 = *(const bf16x8*)&row[1024 + qq*16];
            b1 = *(const bf16x8*)&row[1024 + qq*16 + 8];
            x0 = *(const bf16x8*)&row[h*64 + qq*16];
            x1 = *(const bf16x8*)&row[h*64 + qq*16 + 8];
        }
        *(bf16x8*)&Ct[r][qq*16]    = c0; *(bf16x8*)&Ct[r][qq*16+8]  = c1;
        *(bf16x8*)&Bt2[r][qq*16]   = b0; *(bf16x8*)&Bt2[r][qq*16+8] = b1;
        short xs[16];
        *(bf16x8*)&xs[0] = x0; *(bf16x8*)&xs[8] = x1;
#pragma unroll
        for (int i = 0; i < 16; i++) Xt[qq*16+i][r] = xs[i];
    }
    __syncthreads();

    const int arow = (wave << 4) + lane15;
    const int trow0 = (wave << 4) + ((lane >> 4) << 2);
    const int scol = lane15;

    // E = C.B^T and I = C.H^T (H from registers)
    f32x4 eacc[4], iacc[4];
#pragma unroll
    for (int j = 0; j < 4; j++) { eacc[j] = (f32x4){0.f,0.f,0.f,0.f}; iacc[j] = (f32x4){0.f,0.f,0.f,0.f}; }
    {
        bf16x8 a0 = *(const bf16x8*)&Ct[arow][koff];
        bf16x8 a1 = *(const bf16x8*)&Ct[arow][32 + koff];
#pragma unroll
        for (int j = 0; j < 4; j++) {
            const int brow = (j << 4) + lane15;
            bf16x8 b0 = *(const bf16x8*)&Bt2[brow][koff];
            bf16x8 b1 = *(const bf16x8*)&Bt2[brow][32 + koff];
            eacc[j] = MFMA(a0, b0, eacc[j]);
            eacc[j] = MFMA(a1, b1, eacc[j]);
            iacc[j] = MFMA(a0, hf0[j], iacc[j]);
            iacc[j] = MFMA(a1, hf1[j], iacc[j]);
        }
    }
    short ebf[4][4];
#pragma unroll
    for (int j = 0; j < 4; j++) {
        int s = j * 16 + scol;
#pragma unroll
        for (int i = 0; i < 4; i++) {
            int t = trow0 + i;
            float val = 0.f;
            if (s <= t) val = eacc[j][i] * expf(cum[t] - cum[s]) * sdt[s];
            ebf[j][i] = f2bf(val);
        }
    }
    __syncthreads();
#pragma unroll
    for (int j = 0; j < 4; j++)
#pragma unroll
        for (int i = 0; i < 4; i++)
            Ct[trow0 + i][j * 16 + scol] = ebf[j][i];
    __syncthreads();

    // Y_intra = E @ X
    f32x4 yacc[4];
#pragma unroll
    for (int j = 0; j < 4; j++) yacc[j] = (f32x4){0.f,0.f,0.f,0.f};
    {
        bf16x8 a0 = *(const bf16x8*)&Ct[arow][koff];
        bf16x8 a1 = *(const bf16x8*)&Ct[arow][32 + koff];
#pragma unroll
        for (int j = 0; j < 4; j++) {
            const int brow = (j << 4) + lane15;
            bf16x8 b0 = *(const bf16x8*)&Xt[brow][koff];
            bf16x8 b1 = *(const bf16x8*)&Xt[brow][32 + koff];
            yacc[j] = MFMA(a0, b0, yacc[j]);
            yacc[j] = MFMA(a1, b1, yacc[j]);
        }
    }
    const float dsk = D_skip[h];
#pragma unroll
    for (int j = 0; j < 4; j++) {
        int p = j * 16 + scol;
#pragma unroll
        for (int i = 0; i < 4; i++) {
            int t = trow0 + i;
            if (t < len) {
                float ce = expf(cum[t]);
                float xv = bf2f(Xt[p][t]);
                float val = yacc[j][i] + ce * iacc[j][i] + dsk * xv;
                ybf[(rowbase + t) * DINNER + h * 64 + p] = f2bf(val);
            }
        }
    }
}

// ------------- gate with silu(z) + RMSNorm; vectorized short4 access -------------
__global__ __launch_bounds__(256) void gate_rmsnorm_kernel(short* __restrict__ y,
                                                           const short* __restrict__ zxb,
                                                           const float* __restrict__ norm_w) {
    const int m = blockIdx.x;
    const int tid = threadIdx.x;
    const int c = tid * 4;
    short4v yv = *(const short4v*)&y[(size_t)m * DINNER + c];
    short4v zv = *(const short4v*)&zxb[(size_t)m * ZW + c];
    float vals[4];
    float ss = 0.f;
#pragma unroll
    for (int i = 0; i < 4; i++) {
        float v = bf2f(yv[i]);
        float z = bf2f(zv[i]);
        float g = v * (z / (1.f + expf(-z)));
        vals[i] = g;
        ss += g * g;
    }
#pragma unroll
    for (int mask = 1; mask < 64; mask <<= 1) ss += __shfl_xor(ss, mask);
    __shared__ float red[4];
    if ((tid & 63) == 0) red[tid >> 6] = ss;
    __syncthreads();
    float tot = red[0] + red[1] + red[2] + red[3];
    float scale = rsqrtf(tot / 1024.f + 1e-5f);
    short4v ov;
#pragma unroll
    for (int i = 0; i < 4; i++) ov[i] = f2bf(vals[i] * scale * norm_w[c + i]);
    *(short4v*)&y[(size_t)m * DINNER + c] = ov;
}

extern "C" void kernel_launch(void* const* d_in, const int* in_sizes, int n_in,
                              void* d_out, int out_size, void* d_ws, size_t ws_size,
                              hipStream_t stream) {
    const float* x          = (const float*)d_in[0];
    const float* in_proj_w  = (const float*)d_in[1];
    const float* conv_w     = (const float*)d_in[2];
    const float* conv_b     = (const float*)d_in[3];
    const float* dt_bias    = (const float*)d_in[4];
    const float* A_log      = (const float*)d_in[5];
    const float* D_skip     = (const float*)d_in[6];
    const float* norm_w     = (const float*)d_in[7];
    const float* out_proj_w = (const float*)d_in[8];
    float* out = (float*)d_out;

    short* zxb   = (short*)d_ws;                              // NROWS*ZW bf16
    short* convo = zxb + (size_t)NROWS * ZW;                  // NROWS*CONVDIM bf16
    short* ybf   = convo + (size_t)NROWS * CONVDIM;           // NROWS*1024 bf16
    short* Hbf   = ybf + (size_t)NROWS * DINNER;              // 2048*4096 bf16
    short* Sbf   = Hbf + (size_t)2048 * 4096;                 // 2048*4096 bf16
    float* lab   = (float*)(Sbf + (size_t)2048 * 4096);       // NROWS*16 f32
    float* atotb = lab + (size_t)NROWS * NHEADS;              // 2048 f32
    short* w2t   = (short*)(atotb + 2048);                    // [512][1024] bf16
    // transient aliases (dead before hosts written):
    short* xb  = convo;                                       // NROWS*512 bf16, dead after K1
    short* w1t = xb + (size_t)NROWS * DMODEL;                 // 2192*512 bf16, dead after K1

    // prep: one fused launch (convert + both weight transposes)
    prep_kernel<<<NCV + NT1 + NT2, 256, 0, stream>>>(x, in_proj_w, out_proj_w, xb, w1t, w2t);

    // K1: in_proj GEMM (64x64, gload_lds); cols <2176 -> bf16 zxb, >=2176 -> fp32 la (fused)
    {
        dim3 g((NROWS + 63) / 64, (DINPROJ + 63) / 64);       // 128 x 35 (x=M fast)
        gemm_bf16<true><<<g, 256, 0, stream>>>(xb, w1t, zxb, NROWS, DINPROJ, DMODEL,
                                               ZW, lab, dt_bias, A_log);
    }

    // K2: conv + silu (bf16 in/out, 2 channels/thread, grid-stride)
    conv_silu_kernel<<<2048, 256, 0, stream>>>(zxb, conv_w, conv_b, convo);

    // K3a: chunk states (bf16)
    chunk_state_kernel<<<BATCH * NCHUNK * NHEADS, 256, 0, stream>>>(
        convo, lab, A_log, Sbf, atotb);

    // K3b: inter-chunk recurrence -> bf16 Hprev (2 elems/thread)
    chunk_state_scan_kernel<<<(64 * 2048) / 256, 256, 0, stream>>>(Sbf, atotb, Hbf);

    // K3c: fused intra + inter + D-skip -> bf16 y (H in registers)
    chunk_yfuse_kernel<<<BATCH * NCHUNK * NHEADS, 256, 0, stream>>>(
        convo, lab, A_log, D_skip, Hbf, ybf);

    // K4: gate + rmsnorm (in place, bf16, vectorized)
    gate_rmsnorm_kernel<<<NROWS, 256, 0, stream>>>(ybf, zxb, norm_w);

    // K5: out = ybf @ out_proj_w (64x64, gload_lds)
    {
        dim3 g((NROWS + 63) / 64, (DMODEL + 63) / 64);        // 128 x 8 (x=M fast)
        gemm_bf16<false><<<g, 256, 0, stream>>>(ybf, w2t, out, NROWS, DMODEL, DINNER,
                                                DMODEL, nullptr, nullptr, nullptr);
    }
}